// Round 1
// baseline (983.873 us; speedup 1.0000x reference)
//
#include <hip/hip_runtime.h>
#include <math.h>

#define G_N 2048
#define RCHUNK 128

// ---------------------------------------------------------------------------
// Precompute per-stage splat params with order-preserving compaction.
// grid = 2 blocks (one per stage), 256 threads.
// params[s]: [2048][8] = {u, v, A, B, C, op, pthr, gid-as-float}
// ---------------------------------------------------------------------------
__global__ void gls_precompute(const float* __restrict__ means,
                               const float* __restrict__ cov6,
                               const float* __restrict__ opac,
                               float* __restrict__ params,
                               int* __restrict__ counts)
{
    int s = blockIdx.x;
    int tid = threadIdx.x;
    __shared__ int s_base;
    __shared__ int s_wsum[4];
    if (tid == 0) s_base = 0;
    __syncthreads();
    float* P = params + s * G_N * 8;
    float H = (float)(100 << s);
    float sh = (float)(1 << s);
    for (int it = 0; it < G_N / 256; ++it) {
        int g = it * 256 + tid;
        float mx = means[g * 3 + 0], my = means[g * 3 + 1], mz = means[g * 3 + 2];
        float op = opac[g * 2 + s];
        bool mask = (mx >= -50.f && mx <= 50.f && my >= -50.f && my <= 50.f &&
                     mz >= -4.f && mz <= 4.f && op > 0.05f);
        unsigned long long bal = __ballot(mask);
        int lane = tid & 63, wid = tid >> 6;
        int prefix = __popcll(bal & ((1ull << lane) - 1ull));
        if (lane == 0) s_wsum[wid] = __popcll(bal);
        __syncthreads();
        int woff = 0;
        for (int w = 0; w < 4; ++w) if (w < wid) woff += s_wsum[w];
        int pos = s_base + woff + prefix;
        if (mask) {
            float u = -sh * my + 0.5f * H;
            float v = -sh * mx + 0.5f * H;
            float a = sh * sh * cov6[g * 6 + 3] + 0.3f;
            float c = sh * sh * cov6[g * 6 + 0] + 0.3f;
            float bb = sh * sh * cov6[g * 6 + 1];
            float det = fmaxf(a * c - bb * bb, 1e-8f);
            P[pos * 8 + 0] = u;
            P[pos * 8 + 1] = v;
            P[pos * 8 + 2] = c / det;
            P[pos * 8 + 3] = -bb / det;
            P[pos * 8 + 4] = a / det;
            P[pos * 8 + 5] = op;
            P[pos * 8 + 6] = -logf(255.f * op);   // power >= pthr <=> alpha >= 1/255
            P[pos * 8 + 7] = __int_as_float(g);
        }
        __syncthreads();
        if (tid == 0) s_base += s_wsum[0] + s_wsum[1] + s_wsum[2] + s_wsum[3];
        __syncthreads();
    }
    if (tid == 0) counts[s] = s_base;
}

// ---------------------------------------------------------------------------
// Render both stages. grid = (13,13,2), block = 256 (16x16 pixel tile).
// Sequential front-to-back compositing per pixel (== reference's scan).
// ---------------------------------------------------------------------------
__global__ __launch_bounds__(256) void gls_render(
    const float* __restrict__ params, const int* __restrict__ counts,
    const float* __restrict__ feats, float* __restrict__ out0,
    float* __restrict__ out1)
{
    int s = blockIdx.z;
    int H = 100 << s;
    if ((int)blockIdx.x * 16 >= H || (int)blockIdx.y * 16 >= H) return;
    const float* P = params + s * G_N * 8;
    float* out = s ? out1 : out0;
    int cnt = counts[s];

    __shared__ float sp[RCHUNK * 8];
    int tid = threadIdx.x;
    int px = blockIdx.x * 16 + (tid & 15);
    int py = blockIdx.y * 16 + (tid >> 4);
    bool active = (px < H) && (py < H);
    float fx = (float)px, fy = (float)py;
    float acc[64];
#pragma unroll
    for (int d = 0; d < 64; ++d) acc[d] = 0.f;
    float T = 1.f;

    for (int base = 0; base < cnt; base += RCHUNK) {
        __syncthreads();
        int i4 = base * 8 + tid * 4;
        if (i4 < cnt * 8) {
            float4 v = *(const float4*)(P + i4);
            *(float4*)(sp + tid * 4) = v;
        }
        __syncthreads();
        int n = min(RCHUNK, cnt - base);
        if (active && T > 1e-6f) {
            for (int j = 0; j < n; ++j) {
                const float* q = sp + j * 8;
                float dx = q[0] - fx, dy = q[1] - fy;
                float power = -0.5f * (q[2] * dx * dx + q[4] * dy * dy) - q[3] * dx * dy;
                if (power <= 0.f && power >= q[6]) {
                    float alpha = fminf(q[5] * __expf(power), 0.99f);
                    float wgt = alpha * T;
                    const float* f = feats + __float_as_int(q[7]) * 64;
#pragma unroll
                    for (int d = 0; d < 64; ++d) acc[d] = fmaf(wgt, f[d], acc[d]);
                    T *= (1.f - alpha);
                }
            }
        }
    }
    if (active) {
#pragma unroll
        for (int d = 0; d < 64; ++d) out[(d * H + py) * H + px] = acc[d];
    }
}

// ---------------------------------------------------------------------------
// Conv3x3 64->64, SAME zero pad, NCHW, f32. Block = 256 threads computes an
// 8x8 spatial tile x all 64 out channels; thread = 4 ch x 4 px microtile.
// Input channels processed in 4 chunks of 16 staged through LDS.
// mode: 0 = none, 1 = relu, 2 = relu(conv + add), 3 = conv + add,
//       4 = conv + bev_emb[(y*W+x)*64 + c]
// ---------------------------------------------------------------------------
__global__ __launch_bounds__(256) void gls_conv3x3(
    const float* __restrict__ in, const float* __restrict__ w,
    const float* __restrict__ add, float* __restrict__ out,
    int H, int mode)
{
    __shared__ float xs[16 * 10 * 12];   // [ci][yy(10)][xx pad->12]
    __shared__ float ws_[144 * 68];      // [k = i*9+kk][o pad->68]
    int tid = threadIdx.x;
    int ty = tid >> 4, tx = tid & 15;
    int o0 = ty * 4;
    int pr = tx >> 1, pc0 = (tx & 1) * 4;
    int y0 = blockIdx.y * 8, x0 = blockIdx.x * 8;
    float acc[4][4];
#pragma unroll
    for (int a = 0; a < 4; ++a)
#pragma unroll
        for (int b = 0; b < 4; ++b) acc[a][b] = 0.f;

    for (int cc = 0; cc < 4; ++cc) {
        int ci0 = cc * 16;
        __syncthreads();
        // stage input tile (16 ch x 10x10 halo), zero pad OOB
        for (int idx = tid; idx < 1600; idx += 256) {
            int ci = idx / 100; int rem = idx - ci * 100;
            int yy = rem / 10; int xx = rem - yy * 10;
            int gy = y0 - 1 + yy, gx = x0 - 1 + xx;
            float v = 0.f;
            if (gy >= 0 && gy < H && gx >= 0 && gx < H)
                v = in[((ci0 + ci) * H + gy) * H + gx];
            xs[(ci * 10 + yy) * 12 + xx] = v;
        }
        // stage weights transposed to [k][o]
        for (int idx = tid; idx < 9216; idx += 256) {
            int o = idx / 144; int kk = idx - o * 144;  // kk = i*9 + k9
            int i = kk / 9; int k9 = kk - i * 9;
            ws_[kk * 68 + o] = w[(o * 64 + ci0 + i) * 9 + k9];
        }
        __syncthreads();
#pragma unroll 1
        for (int i = 0; i < 16; ++i) {
            float4 wreg[9];
#pragma unroll
            for (int t = 0; t < 9; ++t)
                wreg[t] = *(const float4*)&ws_[(i * 9 + t) * 68 + o0];
#pragma unroll
            for (int ky = 0; ky < 3; ++ky) {
                const float* row = &xs[(i * 10 + pr + ky) * 12 + pc0];
                float4 xa = *(const float4*)row;
                float2 xb = *(const float2*)(row + 4);
                float xr[6] = {xa.x, xa.y, xa.z, xa.w, xb.x, xb.y};
#pragma unroll
                for (int kx = 0; kx < 3; ++kx) {
                    float4 wv = wreg[ky * 3 + kx];
#pragma unroll
                    for (int p = 0; p < 4; ++p) {
                        float xv = xr[kx + p];
                        acc[0][p] = fmaf(wv.x, xv, acc[0][p]);
                        acc[1][p] = fmaf(wv.y, xv, acc[1][p]);
                        acc[2][p] = fmaf(wv.z, xv, acc[2][p]);
                        acc[3][p] = fmaf(wv.w, xv, acc[3][p]);
                    }
                }
            }
        }
    }
    int gy = y0 + pr;
    if (gy < H) {
#pragma unroll
        for (int c = 0; c < 4; ++c) {
            int o = o0 + c;
#pragma unroll
            for (int p = 0; p < 4; ++p) {
                int gx = x0 + pc0 + p;
                if (gx < H) {
                    int idxo = (o * H + gy) * H + gx;
                    float v = acc[c][p];
                    if (mode == 1) v = fmaxf(v, 0.f);
                    else if (mode == 2) v = fmaxf(v + add[idxo], 0.f);
                    else if (mode == 3) v = v + add[idxo];
                    else if (mode == 4) v = v + add[(gy * H + gx) * 64 + o];
                    out[idxo] = v;
                }
            }
        }
    }
}

// ---------------------------------------------------------------------------
// Bilinear 2x upsample (100 -> 200), jax.image.resize half-pixel semantics.
// ---------------------------------------------------------------------------
__global__ void gls_upsample(const float* __restrict__ in, float* __restrict__ out)
{
    int idx = blockIdx.x * 256 + threadIdx.x;
    if (idx >= 64 * 200 * 200) return;
    int c = idx / 40000; int rem = idx - c * 40000;
    int y = rem / 200; int x = rem - y * 200;
    int yi = y >> 1, xi = x >> 1;
    int yb = (y & 1) ? min(yi + 1, 99) : max(yi - 1, 0);
    int xb = (x & 1) ? min(xi + 1, 99) : max(xi - 1, 0);
    const float* p = in + c * 10000;
    out[idx] = 0.5625f * p[yi * 100 + xi] + 0.1875f * p[yi * 100 + xb]
             + 0.1875f * p[yb * 100 + xi] + 0.0625f * p[yb * 100 + xb];
}

// ---------------------------------------------------------------------------
// Instance norm: per-channel mean / inv-std over 200x200. 64 blocks.
// ---------------------------------------------------------------------------
__global__ __launch_bounds__(256) void gls_in_reduce(const float* __restrict__ y,
                                                     float* __restrict__ stats)
{
    int c = blockIdx.x;
    const float* p = y + c * 40000;
    float s = 0.f, s2 = 0.f;
    for (int i = threadIdx.x; i < 40000; i += 256) {
        float v = p[i];
        s += v;
        s2 = fmaf(v, v, s2);
    }
    __shared__ float ls[256], ls2[256];
    ls[threadIdx.x] = s; ls2[threadIdx.x] = s2;
    __syncthreads();
    for (int off = 128; off > 0; off >>= 1) {
        if (threadIdx.x < off) {
            ls[threadIdx.x] += ls[threadIdx.x + off];
            ls2[threadIdx.x] += ls2[threadIdx.x + off];
        }
        __syncthreads();
    }
    if (threadIdx.x == 0) {
        float mean = ls[0] / 40000.f;
        float var = ls2[0] / 40000.f - mean * mean;
        stats[c] = mean;
        stats[64 + c] = rsqrtf(var + 1e-5f);
    }
}

__global__ void gls_normadd(const float* __restrict__ y, const float* __restrict__ stats,
                            const float* __restrict__ c1, float* __restrict__ out)
{
    int idx = blockIdx.x * 256 + threadIdx.x;
    if (idx >= 2560000) return;
    int c = idx / 40000;
    out[idx] = (y[idx] - stats[c]) * stats[64 + c] + c1[idx];
}

__global__ void gls_numg(const int* __restrict__ counts, float* __restrict__ out)
{
    if (threadIdx.x == 0 && blockIdx.x == 0)
        out[0] = (float)(counts[0] + counts[1]);
}

// ---------------------------------------------------------------------------
extern "C" void kernel_launch(void* const* d_in, const int* in_sizes, int n_in,
                              void* d_out, int out_size, void* d_ws, size_t ws_size,
                              hipStream_t stream)
{
    const float* feats   = (const float*)d_in[0];  // (1,2048,64)
    const float* means   = (const float*)d_in[1];  // (1,2048,3)
    const float* cov6    = (const float*)d_in[2];  // (1,2048,6)
    const float* opac    = (const float*)d_in[3];  // (1,2048,2)
    const float* bev_emb = (const float*)d_in[4];  // (10000,64)
    const float* conv1_w = (const float*)d_in[5];  // (2,64,64,3,3)
    const float* blk_w   = (const float*)d_in[6];  // (2,2,2,64,64,3,3)
    const float* up_w    = (const float*)d_in[7];  // (1,64,64,3,3)
    float* out = (float*)d_out;
    float* ws = (float*)d_ws;

    const int WCONV = 64 * 64 * 9;  // 36864

    float* P     = ws;                  // 2*2048*8 = 32768
    int*   cnts  = (int*)(ws + 32768);  // 2 ints
    float* stats = ws + 33024;          // 128
    float* R0 = ws + 65536;             // 640000 (bev stage 0)
    float* A0 = ws + 720896;            // 640000
    float* T0 = ws + 1376256;           // 640000
    float* B0 = ws + 2031616;           // 640000
    float* Q0 = ws + 2686976;           // 2560000 (bev stage 1 / x)
    float* Q1 = ws + 5308416;           // 2560000
    float* Q2 = ws + 7929856;           // 2560000
    float* Q3 = ws + 10551296;          // 2560000

    gls_precompute<<<dim3(2), 256, 0, stream>>>(means, cov6, opac, P, cnts);
    gls_render<<<dim3(13, 13, 2), 256, 0, stream>>>(P, cnts, feats, R0, Q0);

    // stage 0: x = conv(bev0) + bev_emb, then 2 basic blocks (H=100)
    gls_conv3x3<<<dim3(13, 13), 256, 0, stream>>>(R0, conv1_w + 0 * WCONV, bev_emb, A0, 100, 4);
    gls_conv3x3<<<dim3(13, 13), 256, 0, stream>>>(A0, blk_w + 0 * WCONV, nullptr, T0, 100, 1);
    gls_conv3x3<<<dim3(13, 13), 256, 0, stream>>>(T0, blk_w + 1 * WCONV, A0, B0, 100, 2);
    gls_conv3x3<<<dim3(13, 13), 256, 0, stream>>>(B0, blk_w + 2 * WCONV, nullptr, T0, 100, 1);
    gls_conv3x3<<<dim3(13, 13), 256, 0, stream>>>(T0, blk_w + 3 * WCONV, B0, A0, 100, 2);

    // stage 1 skip: conv(bev1)  (H=200)
    gls_conv3x3<<<dim3(25, 25), 256, 0, stream>>>(Q0, conv1_w + 1 * WCONV, nullptr, Q1, 200, 0);
    // upsample x (100->200), conv, instance-norm, + skip
    gls_upsample<<<10000, 256, 0, stream>>>(A0, Q2);
    gls_conv3x3<<<dim3(25, 25), 256, 0, stream>>>(Q2, up_w, nullptr, Q3, 200, 0);
    gls_in_reduce<<<64, 256, 0, stream>>>(Q3, stats);
    gls_normadd<<<10000, 256, 0, stream>>>(Q3, stats, Q1, Q0);
    // stage 1: 2 basic blocks (H=200), final conv writes d_out
    gls_conv3x3<<<dim3(25, 25), 256, 0, stream>>>(Q0, blk_w + 4 * WCONV, nullptr, Q2, 200, 1);
    gls_conv3x3<<<dim3(25, 25), 256, 0, stream>>>(Q2, blk_w + 5 * WCONV, Q0, Q1, 200, 2);
    gls_conv3x3<<<dim3(25, 25), 256, 0, stream>>>(Q1, blk_w + 6 * WCONV, nullptr, Q2, 200, 1);
    gls_conv3x3<<<dim3(25, 25), 256, 0, stream>>>(Q2, blk_w + 7 * WCONV, Q1, out, 200, 2);

    gls_numg<<<1, 64, 0, stream>>>(cnts, out + 2560000);
    (void)in_sizes; (void)n_in; (void)out_size; (void)ws_size;
}

// Round 2
// 841.450 us; speedup vs baseline: 1.1693x; 1.1693x over previous
//
#include <hip/hip_runtime.h>
#include <math.h>

#define G_N 2048
#define CCH 256
#define PSTR 12   // params stride: {u,v,A,B,C,op,pthr,gid, rx,ry, pad,pad}

// ---------------------------------------------------------------------------
// Precompute per-stage splat params with order-preserving compaction.
// grid = 2 blocks (one per stage), 256 threads.
// ---------------------------------------------------------------------------
__global__ void gls_precompute(const float* __restrict__ means,
                               const float* __restrict__ cov6,
                               const float* __restrict__ opac,
                               float* __restrict__ params,
                               int* __restrict__ counts)
{
    int s = blockIdx.x;
    int tid = threadIdx.x;
    __shared__ int s_base;
    __shared__ int s_wsum[4];
    if (tid == 0) s_base = 0;
    __syncthreads();
    float* P = params + s * G_N * PSTR;
    float H = (float)(100 << s);
    float sh = (float)(1 << s);
    for (int it = 0; it < G_N / 256; ++it) {
        int g = it * 256 + tid;
        float mx = means[g * 3 + 0], my = means[g * 3 + 1], mz = means[g * 3 + 2];
        float op = opac[g * 2 + s];
        bool mask = (mx >= -50.f && mx <= 50.f && my >= -50.f && my <= 50.f &&
                     mz >= -4.f && mz <= 4.f && op > 0.05f);
        unsigned long long bal = __ballot(mask);
        int lane = tid & 63, wid = tid >> 6;
        int prefix = __popcll(bal & ((1ull << lane) - 1ull));
        if (lane == 0) s_wsum[wid] = __popcll(bal);
        __syncthreads();
        int woff = 0;
        for (int w = 0; w < 4; ++w) if (w < wid) woff += s_wsum[w];
        int pos = s_base + woff + prefix;
        if (mask) {
            float u = -sh * my + 0.5f * H;
            float v = -sh * mx + 0.5f * H;
            float a = sh * sh * cov6[g * 6 + 3] + 0.3f;
            float c = sh * sh * cov6[g * 6 + 0] + 0.3f;
            float bb = sh * sh * cov6[g * 6 + 1];
            float det = fmaxf(a * c - bb * bb, 1e-8f);
            float t = logf(255.f * op);          // > 0 since op > 0.05
            float* Q = P + pos * PSTR;
            Q[0] = u;
            Q[1] = v;
            Q[2] = c / det;
            Q[3] = -bb / det;
            Q[4] = a / det;
            Q[5] = op;
            Q[6] = -t;                            // pthr
            Q[7] = __int_as_float(g);
            Q[8] = sqrtf(2.f * t * a);            // rx: |dx| bound of alpha>=1/255 ellipse
            Q[9] = sqrtf(2.f * t * c);            // ry
            Q[10] = 0.f; Q[11] = 0.f;
        }
        __syncthreads();
        if (tid == 0) s_base += s_wsum[0] + s_wsum[1] + s_wsum[2] + s_wsum[3];
        __syncthreads();
    }
    if (tid == 0) counts[s] = s_base;
}

// ---------------------------------------------------------------------------
// Render both stages. grid = (13,13,2), block = 256 (16x16 pixel tile).
// Per chunk of 256 gaussians: cooperative LDS load, per-tile bbox cull with
// order-preserving ballot compaction, then per-pixel front-to-back composite
// over the (small) surviving list.
// ---------------------------------------------------------------------------
__global__ __launch_bounds__(256) void gls_render(
    const float* __restrict__ params, const int* __restrict__ counts,
    const float* __restrict__ feats, float* __restrict__ out0,
    float* __restrict__ out1)
{
    int s = blockIdx.z;
    int H = 100 << s;
    if ((int)blockIdx.x * 16 >= H || (int)blockIdx.y * 16 >= H) return;
    const float* P = params + s * G_N * PSTR;
    float* out = s ? out1 : out0;
    int cnt = counts[s];

    __shared__ float raw[CCH * PSTR];
    __shared__ float cmp[CCH * PSTR];
    __shared__ int s_wsum[4];
    int tid = threadIdx.x;
    int px = blockIdx.x * 16 + (tid & 15);
    int py = blockIdx.y * 16 + (tid >> 4);
    bool active = (px < H) && (py < H);
    float fx = (float)px, fy = (float)py;
    float tx0 = (float)(blockIdx.x * 16);
    float tx1 = (float)min(H - 1, (int)blockIdx.x * 16 + 15);
    float ty0 = (float)(blockIdx.y * 16);
    float ty1 = (float)min(H - 1, (int)blockIdx.y * 16 + 15);

    float acc[64];
#pragma unroll
    for (int d = 0; d < 64; ++d) acc[d] = 0.f;
    float T = 1.f;

    for (int base = 0; base < cnt; base += CCH) {
        int anyalive = __syncthreads_or((int)(active && T > 1e-6f));
        if (!anyalive) break;
        int n = min(CCH, cnt - base);
        // cooperative load of chunk (n * PSTR floats = n*3 float4)
        for (int i = tid; i < n * 3; i += 256)
            ((float4*)raw)[i] = ((const float4*)(P + base * PSTR))[i];
        __syncthreads();
        // bbox-vs-tile cull, one gaussian per thread
        bool pass = false;
        if (tid < n) {
            float u = raw[tid * PSTR + 0], v = raw[tid * PSTR + 1];
            float rx = raw[tid * PSTR + 8], ry = raw[tid * PSTR + 9];
            pass = (u + rx >= tx0) && (u - rx <= tx1) &&
                   (v + ry >= ty0) && (v - ry <= ty1);
        }
        unsigned long long bal = __ballot(pass);
        int lane = tid & 63, wid = tid >> 6;
        int prefix = __popcll(bal & ((1ull << lane) - 1ull));
        if (lane == 0) s_wsum[wid] = __popcll(bal);
        __syncthreads();
        int woff = 0;
        for (int w = 0; w < 4; ++w) if (w < wid) woff += s_wsum[w];
        if (pass) {
            float4* dst = (float4*)(cmp + (woff + prefix) * PSTR);
            const float4* src = (const float4*)(raw + tid * PSTR);
            dst[0] = src[0]; dst[1] = src[1]; dst[2] = src[2];
        }
        __syncthreads();
        int nc = s_wsum[0] + s_wsum[1] + s_wsum[2] + s_wsum[3];
        if (active && T > 1e-6f) {
            for (int j = 0; j < nc; ++j) {
                float4 q0 = *(const float4*)(cmp + j * PSTR);      // u,v,A,B
                float4 q1 = *(const float4*)(cmp + j * PSTR + 4);  // C,op,pthr,gid
                float dx = q0.x - fx, dy = q0.y - fy;
                float power = -0.5f * (q0.z * dx * dx + q1.x * dy * dy) - q0.w * dx * dy;
                if (power <= 0.f && power >= q1.z) {
                    float alpha = fminf(q1.y * __expf(power), 0.99f);
                    float wgt = alpha * T;
                    const float* f = feats + __float_as_int(q1.w) * 64;
#pragma unroll
                    for (int d = 0; d < 64; ++d) acc[d] = fmaf(wgt, f[d], acc[d]);
                    T *= (1.f - alpha);
                }
            }
        }
    }
    if (active) {
#pragma unroll
        for (int d = 0; d < 64; ++d) out[(d * H + py) * H + px] = acc[d];
    }
}

// ---------------------------------------------------------------------------
// Conv3x3 64->64, SAME zero pad, NCHW, f32. Block = 256 threads computes an
// 8x8 spatial tile x all 64 out channels; thread = 4 ch x 4 px microtile.
// mode: 0 = none, 1 = relu, 2 = relu(conv + add), 3 = conv + add,
//       4 = conv + bev_emb[(y*W+x)*64 + c]
// ---------------------------------------------------------------------------
__global__ __launch_bounds__(256) void gls_conv3x3(
    const float* __restrict__ in, const float* __restrict__ w,
    const float* __restrict__ add, float* __restrict__ out,
    int H, int mode)
{
    __shared__ float xs[16 * 10 * 12];   // [ci][yy(10)][xx pad->12]
    __shared__ float ws_[144 * 68];      // [k = i*9+kk][o pad->68]
    int tid = threadIdx.x;
    int ty = tid >> 4, tx = tid & 15;
    int o0 = ty * 4;
    int pr = tx >> 1, pc0 = (tx & 1) * 4;
    int y0 = blockIdx.y * 8, x0 = blockIdx.x * 8;
    float acc[4][4];
#pragma unroll
    for (int a = 0; a < 4; ++a)
#pragma unroll
        for (int b = 0; b < 4; ++b) acc[a][b] = 0.f;

    for (int cc = 0; cc < 4; ++cc) {
        int ci0 = cc * 16;
        __syncthreads();
        for (int idx = tid; idx < 1600; idx += 256) {
            int ci = idx / 100; int rem = idx - ci * 100;
            int yy = rem / 10; int xx = rem - yy * 10;
            int gy = y0 - 1 + yy, gx = x0 - 1 + xx;
            float v = 0.f;
            if (gy >= 0 && gy < H && gx >= 0 && gx < H)
                v = in[((ci0 + ci) * H + gy) * H + gx];
            xs[(ci * 10 + yy) * 12 + xx] = v;
        }
        for (int idx = tid; idx < 9216; idx += 256) {
            int o = idx / 144; int kk = idx - o * 144;
            int i = kk / 9; int k9 = kk - i * 9;
            ws_[kk * 68 + o] = w[(o * 64 + ci0 + i) * 9 + k9];
        }
        __syncthreads();
#pragma unroll 1
        for (int i = 0; i < 16; ++i) {
            float4 wreg[9];
#pragma unroll
            for (int t = 0; t < 9; ++t)
                wreg[t] = *(const float4*)&ws_[(i * 9 + t) * 68 + o0];
#pragma unroll
            for (int ky = 0; ky < 3; ++ky) {
                const float* row = &xs[(i * 10 + pr + ky) * 12 + pc0];
                float4 xa = *(const float4*)row;
                float2 xb = *(const float2*)(row + 4);
                float xr[6] = {xa.x, xa.y, xa.z, xa.w, xb.x, xb.y};
#pragma unroll
                for (int kx = 0; kx < 3; ++kx) {
                    float4 wv = wreg[ky * 3 + kx];
#pragma unroll
                    for (int p = 0; p < 4; ++p) {
                        float xv = xr[kx + p];
                        acc[0][p] = fmaf(wv.x, xv, acc[0][p]);
                        acc[1][p] = fmaf(wv.y, xv, acc[1][p]);
                        acc[2][p] = fmaf(wv.z, xv, acc[2][p]);
                        acc[3][p] = fmaf(wv.w, xv, acc[3][p]);
                    }
                }
            }
        }
    }
    int gy = y0 + pr;
    if (gy < H) {
#pragma unroll
        for (int c = 0; c < 4; ++c) {
            int o = o0 + c;
#pragma unroll
            for (int p = 0; p < 4; ++p) {
                int gx = x0 + pc0 + p;
                if (gx < H) {
                    int idxo = (o * H + gy) * H + gx;
                    float v = acc[c][p];
                    if (mode == 1) v = fmaxf(v, 0.f);
                    else if (mode == 2) v = fmaxf(v + add[idxo], 0.f);
                    else if (mode == 3) v = v + add[idxo];
                    else if (mode == 4) v = v + add[(gy * H + gx) * 64 + o];
                    out[idxo] = v;
                }
            }
        }
    }
}

// ---------------------------------------------------------------------------
__global__ void gls_upsample(const float* __restrict__ in, float* __restrict__ out)
{
    int idx = blockIdx.x * 256 + threadIdx.x;
    if (idx >= 64 * 200 * 200) return;
    int c = idx / 40000; int rem = idx - c * 40000;
    int y = rem / 200; int x = rem - y * 200;
    int yi = y >> 1, xi = x >> 1;
    int yb = (y & 1) ? min(yi + 1, 99) : max(yi - 1, 0);
    int xb = (x & 1) ? min(xi + 1, 99) : max(xi - 1, 0);
    const float* p = in + c * 10000;
    out[idx] = 0.5625f * p[yi * 100 + xi] + 0.1875f * p[yi * 100 + xb]
             + 0.1875f * p[yb * 100 + xi] + 0.0625f * p[yb * 100 + xb];
}

__global__ __launch_bounds__(256) void gls_in_reduce(const float* __restrict__ y,
                                                     float* __restrict__ stats)
{
    int c = blockIdx.x;
    const float* p = y + c * 40000;
    float s = 0.f, s2 = 0.f;
    for (int i = threadIdx.x; i < 40000; i += 256) {
        float v = p[i];
        s += v;
        s2 = fmaf(v, v, s2);
    }
    __shared__ float ls[256], ls2[256];
    ls[threadIdx.x] = s; ls2[threadIdx.x] = s2;
    __syncthreads();
    for (int off = 128; off > 0; off >>= 1) {
        if (threadIdx.x < off) {
            ls[threadIdx.x] += ls[threadIdx.x + off];
            ls2[threadIdx.x] += ls2[threadIdx.x + off];
        }
        __syncthreads();
    }
    if (threadIdx.x == 0) {
        float mean = ls[0] / 40000.f;
        float var = ls2[0] / 40000.f - mean * mean;
        stats[c] = mean;
        stats[64 + c] = rsqrtf(var + 1e-5f);
    }
}

__global__ void gls_normadd(const float* __restrict__ y, const float* __restrict__ stats,
                            const float* __restrict__ c1, float* __restrict__ out)
{
    int idx = blockIdx.x * 256 + threadIdx.x;
    if (idx >= 2560000) return;
    int c = idx / 40000;
    out[idx] = (y[idx] - stats[c]) * stats[64 + c] + c1[idx];
}

__global__ void gls_numg(const int* __restrict__ counts, float* __restrict__ out)
{
    if (threadIdx.x == 0 && blockIdx.x == 0)
        out[0] = (float)(counts[0] + counts[1]);
}

// ---------------------------------------------------------------------------
extern "C" void kernel_launch(void* const* d_in, const int* in_sizes, int n_in,
                              void* d_out, int out_size, void* d_ws, size_t ws_size,
                              hipStream_t stream)
{
    const float* feats   = (const float*)d_in[0];
    const float* means   = (const float*)d_in[1];
    const float* cov6    = (const float*)d_in[2];
    const float* opac    = (const float*)d_in[3];
    const float* bev_emb = (const float*)d_in[4];
    const float* conv1_w = (const float*)d_in[5];
    const float* blk_w   = (const float*)d_in[6];
    const float* up_w    = (const float*)d_in[7];
    float* out = (float*)d_out;
    float* ws = (float*)d_ws;

    const int WCONV = 64 * 64 * 9;  // 36864

    float* P     = ws;                  // 2*2048*12 = 49152
    int*   cnts  = (int*)(ws + 49152);  // 2 ints
    float* stats = ws + 49408;          // 128
    float* R0 = ws + 65536;             // 640000 (bev stage 0)
    float* A0 = ws + 720896;
    float* T0 = ws + 1376256;
    float* B0 = ws + 2031616;
    float* Q0 = ws + 2686976;           // 2560000 (bev stage 1 / x)
    float* Q1 = ws + 5308416;
    float* Q2 = ws + 7929856;
    float* Q3 = ws + 10551296;

    gls_precompute<<<dim3(2), 256, 0, stream>>>(means, cov6, opac, P, cnts);
    gls_render<<<dim3(13, 13, 2), 256, 0, stream>>>(P, cnts, feats, R0, Q0);

    // stage 0: x = conv(bev0) + bev_emb, then 2 basic blocks (H=100)
    gls_conv3x3<<<dim3(13, 13), 256, 0, stream>>>(R0, conv1_w + 0 * WCONV, bev_emb, A0, 100, 4);
    gls_conv3x3<<<dim3(13, 13), 256, 0, stream>>>(A0, blk_w + 0 * WCONV, nullptr, T0, 100, 1);
    gls_conv3x3<<<dim3(13, 13), 256, 0, stream>>>(T0, blk_w + 1 * WCONV, A0, B0, 100, 2);
    gls_conv3x3<<<dim3(13, 13), 256, 0, stream>>>(B0, blk_w + 2 * WCONV, nullptr, T0, 100, 1);
    gls_conv3x3<<<dim3(13, 13), 256, 0, stream>>>(T0, blk_w + 3 * WCONV, B0, A0, 100, 2);

    // stage 1 skip: conv(bev1)  (H=200)
    gls_conv3x3<<<dim3(25, 25), 256, 0, stream>>>(Q0, conv1_w + 1 * WCONV, nullptr, Q1, 200, 0);
    gls_upsample<<<10000, 256, 0, stream>>>(A0, Q2);
    gls_conv3x3<<<dim3(25, 25), 256, 0, stream>>>(Q2, up_w, nullptr, Q3, 200, 0);
    gls_in_reduce<<<64, 256, 0, stream>>>(Q3, stats);
    gls_normadd<<<10000, 256, 0, stream>>>(Q3, stats, Q1, Q0);
    // stage 1: 2 basic blocks (H=200), final conv writes d_out
    gls_conv3x3<<<dim3(25, 25), 256, 0, stream>>>(Q0, blk_w + 4 * WCONV, nullptr, Q2, 200, 1);
    gls_conv3x3<<<dim3(25, 25), 256, 0, stream>>>(Q2, blk_w + 5 * WCONV, Q0, Q1, 200, 2);
    gls_conv3x3<<<dim3(25, 25), 256, 0, stream>>>(Q1, blk_w + 6 * WCONV, nullptr, Q2, 200, 1);
    gls_conv3x3<<<dim3(25, 25), 256, 0, stream>>>(Q2, blk_w + 7 * WCONV, Q1, out, 200, 2);

    gls_numg<<<1, 64, 0, stream>>>(cnts, out + 2560000);
    (void)in_sizes; (void)n_in; (void)out_size; (void)ws_size;
}

// Round 3
// 362.814 us; speedup vs baseline: 2.7118x; 2.3192x over previous
//
#include <hip/hip_runtime.h>
#include <math.h>

#define G_N 2048
#define CCH 256
#define PSTR 12   // params stride: {u,v,A,B,C,op,pthr,gid, rx,ry, pad,pad}

typedef short bhalf8 __attribute__((ext_vector_type(8)));
typedef float f32x4 __attribute__((ext_vector_type(4)));

__device__ __forceinline__ unsigned short f2bf(float f) {
    unsigned u = __float_as_uint(f);
    unsigned r = (u + 0x7fffu + ((u >> 16) & 1u)) >> 16;
    return (unsigned short)r;
}

// ---------------------------------------------------------------------------
// Weight prep: convert all 11 conv weight tensors (f32, [oc][ci][3][3]) into
// bf16 A-fragment order: wprep[c][pair(18)][m_tile(4)][lane(64)][j(8)]
//   pair p: tap = p>>1 (ky*3+kx), chunk = p&1 (ci 32-block)
//   oc = m*16 + (lane&15); ci = chunk*32 + (lane>>4)*8 + j
// grid = (18, 11), 256 threads.
// ---------------------------------------------------------------------------
__global__ void gls_wprep(const float* __restrict__ conv1_w,
                          const float* __restrict__ blk_w,
                          const float* __restrict__ up_w,
                          unsigned short* __restrict__ wprep)
{
    const int W = 64 * 64 * 9;
    int p = blockIdx.x, c = blockIdx.y;
    const float* src;
    if (c == 0) src = conv1_w;
    else if (c <= 4) src = blk_w + (c - 1) * W;
    else if (c == 5) src = conv1_w + W;
    else if (c == 6) src = up_w;
    else src = blk_w + (c - 3) * W;
    int tap = p >> 1, ch = p & 1;
    int t = threadIdx.x;
    int m = t >> 6, lane = t & 63;
    int oc = m * 16 + (lane & 15);
    int ci0 = ch * 32 + (lane >> 4) * 8;
    unsigned short v[8];
#pragma unroll
    for (int j = 0; j < 8; ++j)
        v[j] = f2bf(src[(oc * 64 + ci0 + j) * 9 + tap]);
    unsigned short* dst = wprep + ((c * 18 + p) * 4 + m) * 64 * 8 + lane * 8;
#pragma unroll
    for (int j = 0; j < 8; ++j) dst[j] = v[j];
}

// ---------------------------------------------------------------------------
// Precompute per-stage splat params with order-preserving compaction.
// ---------------------------------------------------------------------------
__global__ void gls_precompute(const float* __restrict__ means,
                               const float* __restrict__ cov6,
                               const float* __restrict__ opac,
                               float* __restrict__ params,
                               int* __restrict__ counts)
{
    int s = blockIdx.x;
    int tid = threadIdx.x;
    __shared__ int s_base;
    __shared__ int s_wsum[4];
    if (tid == 0) s_base = 0;
    __syncthreads();
    float* P = params + s * G_N * PSTR;
    float H = (float)(100 << s);
    float sh = (float)(1 << s);
    for (int it = 0; it < G_N / 256; ++it) {
        int g = it * 256 + tid;
        float mx = means[g * 3 + 0], my = means[g * 3 + 1], mz = means[g * 3 + 2];
        float op = opac[g * 2 + s];
        bool mask = (mx >= -50.f && mx <= 50.f && my >= -50.f && my <= 50.f &&
                     mz >= -4.f && mz <= 4.f && op > 0.05f);
        unsigned long long bal = __ballot(mask);
        int lane = tid & 63, wid = tid >> 6;
        int prefix = __popcll(bal & ((1ull << lane) - 1ull));
        if (lane == 0) s_wsum[wid] = __popcll(bal);
        __syncthreads();
        int woff = 0;
        for (int w = 0; w < 4; ++w) if (w < wid) woff += s_wsum[w];
        int pos = s_base + woff + prefix;
        if (mask) {
            float u = -sh * my + 0.5f * H;
            float v = -sh * mx + 0.5f * H;
            float a = sh * sh * cov6[g * 6 + 3] + 0.3f;
            float c = sh * sh * cov6[g * 6 + 0] + 0.3f;
            float bb = sh * sh * cov6[g * 6 + 1];
            float det = fmaxf(a * c - bb * bb, 1e-8f);
            float t = logf(255.f * op);
            float* Q = P + pos * PSTR;
            Q[0] = u;
            Q[1] = v;
            Q[2] = c / det;
            Q[3] = -bb / det;
            Q[4] = a / det;
            Q[5] = op;
            Q[6] = -t;
            Q[7] = __int_as_float(g);
            Q[8] = sqrtf(2.f * t * a);
            Q[9] = sqrtf(2.f * t * c);
            Q[10] = 0.f; Q[11] = 0.f;
        }
        __syncthreads();
        if (tid == 0) s_base += s_wsum[0] + s_wsum[1] + s_wsum[2] + s_wsum[3];
        __syncthreads();
    }
    if (tid == 0) counts[s] = s_base;
}

// ---------------------------------------------------------------------------
// Render both stages: per-tile bbox cull + front-to-back composite.
// ---------------------------------------------------------------------------
__global__ __launch_bounds__(256) void gls_render(
    const float* __restrict__ params, const int* __restrict__ counts,
    const float* __restrict__ feats, float* __restrict__ out0,
    float* __restrict__ out1)
{
    int s = blockIdx.z;
    int H = 100 << s;
    if ((int)blockIdx.x * 16 >= H || (int)blockIdx.y * 16 >= H) return;
    const float* P = params + s * G_N * PSTR;
    float* out = s ? out1 : out0;
    int cnt = counts[s];

    __shared__ float raw[CCH * PSTR];
    __shared__ float cmp[CCH * PSTR];
    __shared__ int s_wsum[4];
    int tid = threadIdx.x;
    int px = blockIdx.x * 16 + (tid & 15);
    int py = blockIdx.y * 16 + (tid >> 4);
    bool active = (px < H) && (py < H);
    float fx = (float)px, fy = (float)py;
    float tx0 = (float)(blockIdx.x * 16);
    float tx1 = (float)min(H - 1, (int)blockIdx.x * 16 + 15);
    float ty0 = (float)(blockIdx.y * 16);
    float ty1 = (float)min(H - 1, (int)blockIdx.y * 16 + 15);

    float acc[64];
#pragma unroll
    for (int d = 0; d < 64; ++d) acc[d] = 0.f;
    float T = 1.f;

    for (int base = 0; base < cnt; base += CCH) {
        int anyalive = __syncthreads_or((int)(active && T > 1e-6f));
        if (!anyalive) break;
        int n = min(CCH, cnt - base);
        for (int i = tid; i < n * 3; i += 256)
            ((float4*)raw)[i] = ((const float4*)(P + base * PSTR))[i];
        __syncthreads();
        bool pass = false;
        if (tid < n) {
            float u = raw[tid * PSTR + 0], v = raw[tid * PSTR + 1];
            float rx = raw[tid * PSTR + 8], ry = raw[tid * PSTR + 9];
            pass = (u + rx >= tx0) && (u - rx <= tx1) &&
                   (v + ry >= ty0) && (v - ry <= ty1);
        }
        unsigned long long bal = __ballot(pass);
        int lane = tid & 63, wid = tid >> 6;
        int prefix = __popcll(bal & ((1ull << lane) - 1ull));
        if (lane == 0) s_wsum[wid] = __popcll(bal);
        __syncthreads();
        int woff = 0;
        for (int w = 0; w < 4; ++w) if (w < wid) woff += s_wsum[w];
        if (pass) {
            float4* dst = (float4*)(cmp + (woff + prefix) * PSTR);
            const float4* src = (const float4*)(raw + tid * PSTR);
            dst[0] = src[0]; dst[1] = src[1]; dst[2] = src[2];
        }
        __syncthreads();
        int nc = s_wsum[0] + s_wsum[1] + s_wsum[2] + s_wsum[3];
        if (active && T > 1e-6f) {
            for (int j = 0; j < nc; ++j) {
                float4 q0 = *(const float4*)(cmp + j * PSTR);
                float4 q1 = *(const float4*)(cmp + j * PSTR + 4);
                float dx = q0.x - fx, dy = q0.y - fy;
                float power = -0.5f * (q0.z * dx * dx + q1.x * dy * dy) - q0.w * dx * dy;
                if (power <= 0.f && power >= q1.z) {
                    float alpha = fminf(q1.y * __expf(power), 0.99f);
                    float wgt = alpha * T;
                    const float* f = feats + __float_as_int(q1.w) * 64;
#pragma unroll
                    for (int d = 0; d < 64; ++d) acc[d] = fmaf(wgt, f[d], acc[d]);
                    T *= (1.f - alpha);
                }
            }
        }
    }
    if (active) {
#pragma unroll
        for (int d = 0; d < 64; ++d) out[(d * H + py) * H + px] = acc[d];
    }
}

// ---------------------------------------------------------------------------
// MFMA conv3x3 64->64, SAME, NCHW f32 in/out, bf16 compute, f32 accum.
// Block = 256 (4 waves): 8x8 spatial x 64 oc. K = 576 split 4-way over waves
// ((tap,chunk) pairs); per K-step each wave does the 4x4 MFMA microtile
// (16 MFMA : 8 LDS b128). 2-level LDS partial reduction, fused epilogue.
// mode: 0 none, 1 relu, 2 relu(conv+add), 4 conv + bev_emb[(y*W+x)*64+c]
// ---------------------------------------------------------------------------
__global__ __launch_bounds__(256) void gls_conv_mfma(
    const float* __restrict__ in, const unsigned short* __restrict__ wprep,
    const float* __restrict__ add, float* __restrict__ out,
    int H, int mode)
{
    __shared__ unsigned short xlds[100 * 72];   // [pos(10x10)][ci], ci-stride 72
    __shared__ float partA[64 * 65];            // [sp][oc] stride 65
    __shared__ float partB[64 * 65];

    int tid = threadIdx.x;
    int w = tid >> 6, lane = tid & 63;
    int n = lane & 15, q = lane >> 4;
    int y0 = blockIdx.y * 8, x0 = blockIdx.x * 8;

    // ---- stage input tile (64ci x 10x10 halo) as bf16 HWC ----
    for (int idx = tid; idx < 1600; idx += 256) {
        int ci4 = idx / 100;          // 0..15 -> ci = 4*ci4
        int pos = idx - ci4 * 100;
        int yy = pos / 10, xx = pos - yy * 10;
        int gy = y0 - 1 + yy, gx = x0 - 1 + xx;
        ushort4 v4 = {0, 0, 0, 0};
        if (gy >= 0 && gy < H && gx >= 0 && gx < H) {
            int ci = ci4 * 4;
            const float* p = in + (ci * H + gy) * H + gx;
            v4.x = f2bf(p[0]);
            v4.y = f2bf(p[(size_t)H * H]);
            v4.z = f2bf(p[2 * (size_t)H * H]);
            v4.w = f2bf(p[3 * (size_t)H * H]);
        }
        *(ushort4*)&xlds[pos * 72 + ci4 * 4] = v4;
    }
    __syncthreads();

    // ---- K loop: pairs p = w, w+4, ... (tap = p>>1, chunk = p&1) ----
    f32x4 acc[4][4];   // [m_tile][n_tile]
#pragma unroll
    for (int m = 0; m < 4; ++m)
#pragma unroll
        for (int t = 0; t < 4; ++t) acc[m][t] = (f32x4){0.f, 0.f, 0.f, 0.f};

    const bhalf8* wp8 = (const bhalf8*)wprep;
    for (int p = w; p < 18; p += 4) {
        int tap = p >> 1, ch = p & 1;
        int dy = tap / 3, dx = tap - dy * 3;
        bhalf8 a[4];
#pragma unroll
        for (int m = 0; m < 4; ++m)
            a[m] = wp8[(p * 4 + m) * 64 + lane];
        bhalf8 b[4];
#pragma unroll
        for (int t = 0; t < 4; ++t) {
            int ly = 2 * t + (n >> 3) + dy;
            int lx = (n & 7) + dx;
            b[t] = *(const bhalf8*)&xlds[(ly * 10 + lx) * 72 + ch * 32 + q * 8];
        }
#pragma unroll
        for (int m = 0; m < 4; ++m)
#pragma unroll
            for (int t = 0; t < 4; ++t)
                acc[m][t] = __builtin_amdgcn_mfma_f32_16x16x32_bf16(a[m], b[t], acc[m][t], 0, 0, 0);
    }

    // ---- partial reduction: waves 2,3 -> LDS; 0,1 absorb; 1 -> LDS; 0 absorbs
    // acc element: sp = t*16 + n, oc = m*16 + q*4 + r
    if (w == 2 || w == 3) {
        float* pt = (w == 2) ? partA : partB;
#pragma unroll
        for (int m = 0; m < 4; ++m)
#pragma unroll
            for (int t = 0; t < 4; ++t)
#pragma unroll
                for (int r = 0; r < 4; ++r)
                    pt[(t * 16 + n) * 65 + m * 16 + q * 4 + r] = acc[m][t][r];
    }
    __syncthreads();
    if (w == 0 || w == 1) {
        const float* pt = (w == 0) ? partA : partB;
#pragma unroll
        for (int m = 0; m < 4; ++m)
#pragma unroll
            for (int t = 0; t < 4; ++t)
#pragma unroll
                for (int r = 0; r < 4; ++r)
                    acc[m][t][r] += pt[(t * 16 + n) * 65 + m * 16 + q * 4 + r];
    }
    __syncthreads();
    if (w == 1) {
#pragma unroll
        for (int m = 0; m < 4; ++m)
#pragma unroll
            for (int t = 0; t < 4; ++t)
#pragma unroll
                for (int r = 0; r < 4; ++r)
                    partA[(t * 16 + n) * 65 + m * 16 + q * 4 + r] = acc[m][t][r];
    }
    __syncthreads();
    if (w == 0) {
#pragma unroll
        for (int m = 0; m < 4; ++m)
#pragma unroll
            for (int t = 0; t < 4; ++t)
#pragma unroll
                for (int r = 0; r < 4; ++r) {
                    int i = (t * 16 + n) * 65 + m * 16 + q * 4 + r;
                    partB[i] = acc[m][t][r] + partA[i];
                }
    }
    __syncthreads();

    // ---- distributed epilogue: wave w stores sp = w*16 + n, oc = q*16 + k
    int sp = w * 16 + n;
    int gy = y0 + (sp >> 3), gx = x0 + (sp & 7);
    if (gy < H && gx < H) {
#pragma unroll
        for (int k = 0; k < 16; ++k) {
            int oc = q * 16 + k;
            float v = partB[sp * 65 + oc];
            int idxo = (oc * H + gy) * H + gx;
            if (mode == 1) v = fmaxf(v, 0.f);
            else if (mode == 2) v = fmaxf(v + add[idxo], 0.f);
            else if (mode == 4) v = v + add[(gy * H + gx) * 64 + oc];
            out[idxo] = v;
        }
    }
}

// ---------------------------------------------------------------------------
__global__ void gls_upsample(const float* __restrict__ in, float* __restrict__ out)
{
    int idx = blockIdx.x * 256 + threadIdx.x;
    if (idx >= 64 * 200 * 200) return;
    int c = idx / 40000; int rem = idx - c * 40000;
    int y = rem / 200; int x = rem - y * 200;
    int yi = y >> 1, xi = x >> 1;
    int yb = (y & 1) ? min(yi + 1, 99) : max(yi - 1, 0);
    int xb = (x & 1) ? min(xi + 1, 99) : max(xi - 1, 0);
    const float* p = in + c * 10000;
    out[idx] = 0.5625f * p[yi * 100 + xi] + 0.1875f * p[yi * 100 + xb]
             + 0.1875f * p[yb * 100 + xi] + 0.0625f * p[yb * 100 + xb];
}

__global__ __launch_bounds__(256) void gls_in_reduce(const float* __restrict__ y,
                                                     float* __restrict__ stats)
{
    int c = blockIdx.x;
    const float* p = y + c * 40000;
    float s = 0.f, s2 = 0.f;
    for (int i = threadIdx.x; i < 40000; i += 256) {
        float v = p[i];
        s += v;
        s2 = fmaf(v, v, s2);
    }
    __shared__ float ls[256], ls2[256];
    ls[threadIdx.x] = s; ls2[threadIdx.x] = s2;
    __syncthreads();
    for (int off = 128; off > 0; off >>= 1) {
        if (threadIdx.x < off) {
            ls[threadIdx.x] += ls[threadIdx.x + off];
            ls2[threadIdx.x] += ls2[threadIdx.x + off];
        }
        __syncthreads();
    }
    if (threadIdx.x == 0) {
        float mean = ls[0] / 40000.f;
        float var = ls2[0] / 40000.f - mean * mean;
        stats[c] = mean;
        stats[64 + c] = rsqrtf(var + 1e-5f);
    }
}

__global__ void gls_normadd(const float* __restrict__ y, const float* __restrict__ stats,
                            const float* __restrict__ c1, float* __restrict__ out)
{
    int idx = blockIdx.x * 256 + threadIdx.x;
    if (idx >= 2560000) return;
    int c = idx / 40000;
    out[idx] = (y[idx] - stats[c]) * stats[64 + c] + c1[idx];
}

__global__ void gls_numg(const int* __restrict__ counts, float* __restrict__ out)
{
    if (threadIdx.x == 0 && blockIdx.x == 0)
        out[0] = (float)(counts[0] + counts[1]);
}

// ---------------------------------------------------------------------------
extern "C" void kernel_launch(void* const* d_in, const int* in_sizes, int n_in,
                              void* d_out, int out_size, void* d_ws, size_t ws_size,
                              hipStream_t stream)
{
    const float* feats   = (const float*)d_in[0];
    const float* means   = (const float*)d_in[1];
    const float* cov6    = (const float*)d_in[2];
    const float* opac    = (const float*)d_in[3];
    const float* bev_emb = (const float*)d_in[4];
    const float* conv1_w = (const float*)d_in[5];
    const float* blk_w   = (const float*)d_in[6];
    const float* up_w    = (const float*)d_in[7];
    float* out = (float*)d_out;
    float* ws = (float*)d_ws;

    const int WC = 64 * 64 * 9;  // 36864 (also wprep elems per conv)

    float* P     = ws;                         // 49152 floats
    int*   cnts  = (int*)(ws + 49152);         // 2
    float* stats = ws + 49408;                 // 128
    unsigned short* wprep = (unsigned short*)(ws + 49664);  // 11*36864 u16 = 202752 floats
    float* R0 = ws + 262144;                   // 640000
    float* A0 = ws + 917504;
    float* T0 = ws + 1572864;
    float* B0 = ws + 2228224;
    float* Q0 = ws + 2883584;                  // 2560000
    float* Q1 = ws + 5505024;
    float* Q2 = ws + 8126464;
    float* Q3 = ws + 10747904;

    gls_wprep<<<dim3(18, 11), 256, 0, stream>>>(conv1_w, blk_w, up_w, wprep);
    gls_precompute<<<dim3(2), 256, 0, stream>>>(means, cov6, opac, P, cnts);
    gls_render<<<dim3(13, 13, 2), 256, 0, stream>>>(P, cnts, feats, R0, Q0);

    // stage 0 (H=100): x = conv(bev0) + bev_emb, then 2 basic blocks
    gls_conv_mfma<<<dim3(13, 13), 256, 0, stream>>>(R0, wprep + 0 * WC, bev_emb, A0, 100, 4);
    gls_conv_mfma<<<dim3(13, 13), 256, 0, stream>>>(A0, wprep + 1 * WC, nullptr, T0, 100, 1);
    gls_conv_mfma<<<dim3(13, 13), 256, 0, stream>>>(T0, wprep + 2 * WC, A0, B0, 100, 2);
    gls_conv_mfma<<<dim3(13, 13), 256, 0, stream>>>(B0, wprep + 3 * WC, nullptr, T0, 100, 1);
    gls_conv_mfma<<<dim3(13, 13), 256, 0, stream>>>(T0, wprep + 4 * WC, B0, A0, 100, 2);

    // stage 1 (H=200)
    gls_conv_mfma<<<dim3(25, 25), 256, 0, stream>>>(Q0, wprep + 5 * WC, nullptr, Q1, 200, 0);
    gls_upsample<<<10000, 256, 0, stream>>>(A0, Q2);
    gls_conv_mfma<<<dim3(25, 25), 256, 0, stream>>>(Q2, wprep + 6 * WC, nullptr, Q3, 200, 0);
    gls_in_reduce<<<64, 256, 0, stream>>>(Q3, stats);
    gls_normadd<<<10000, 256, 0, stream>>>(Q3, stats, Q1, Q0);
    gls_conv_mfma<<<dim3(25, 25), 256, 0, stream>>>(Q0, wprep + 7 * WC, nullptr, Q2, 200, 1);
    gls_conv_mfma<<<dim3(25, 25), 256, 0, stream>>>(Q2, wprep + 8 * WC, Q0, Q1, 200, 2);
    gls_conv_mfma<<<dim3(25, 25), 256, 0, stream>>>(Q1, wprep + 9 * WC, nullptr, Q2, 200, 1);
    gls_conv_mfma<<<dim3(25, 25), 256, 0, stream>>>(Q2, wprep + 10 * WC, Q1, out, 200, 2);

    gls_numg<<<1, 64, 0, stream>>>(cnts, out + 2560000);
    (void)in_sizes; (void)n_in; (void)out_size; (void)ws_size;
}

// Round 4
// 337.695 us; speedup vs baseline: 2.9135x; 1.0744x over previous
//
#include <hip/hip_runtime.h>
#include <math.h>

#define G_N 2048
#define CCH 256
#define PSTR 12   // params stride: {u,v,A,B,C,op,pthr,gid, rx,ry, pad,pad}

typedef short bhalf8 __attribute__((ext_vector_type(8)));
typedef float f32x4 __attribute__((ext_vector_type(4)));

__device__ __forceinline__ unsigned short f2bf(float f) {
    unsigned u = __float_as_uint(f);
    unsigned r = (u + 0x7fffu + ((u >> 16) & 1u)) >> 16;
    return (unsigned short)r;
}

// ---------------------------------------------------------------------------
// Combined prep: blocks 0..197 -> weight repack (p = bx%18, c = bx/18);
// blocks 198,199 -> splat-param precompute (s = bx-198).
// wprep layout: [c][pair(18)][m_tile(4)][lane(64)][j(8)] bf16
//   pair p: tap = p>>1, chunk = p&1; oc = m*16+(lane&15); ci = chunk*32+(lane>>4)*8+j
// ---------------------------------------------------------------------------
__global__ void gls_prep(const float* __restrict__ conv1_w,
                         const float* __restrict__ blk_w,
                         const float* __restrict__ up_w,
                         unsigned short* __restrict__ wprep,
                         const float* __restrict__ means,
                         const float* __restrict__ cov6,
                         const float* __restrict__ opac,
                         float* __restrict__ params,
                         int* __restrict__ counts)
{
    int bx = blockIdx.x;
    if (bx < 198) {
        const int W = 64 * 64 * 9;
        int p = bx % 18, c = bx / 18;
        const float* src;
        if (c == 0) src = conv1_w;
        else if (c <= 4) src = blk_w + (c - 1) * W;
        else if (c == 5) src = conv1_w + W;
        else if (c == 6) src = up_w;
        else src = blk_w + (c - 3) * W;
        int tap = p >> 1;
        int t = threadIdx.x;
        int m = t >> 6, lane = t & 63;
        int oc = m * 16 + (lane & 15);
        int ci0 = (p & 1) * 32 + (lane >> 4) * 8;
        unsigned short v[8];
#pragma unroll
        for (int j = 0; j < 8; ++j)
            v[j] = f2bf(src[(oc * 64 + ci0 + j) * 9 + tap]);
        unsigned short* dst = wprep + ((c * 18 + p) * 4 + m) * 64 * 8 + lane * 8;
#pragma unroll
        for (int j = 0; j < 8; ++j) dst[j] = v[j];
        return;
    }
    // ---- precompute (order-preserving compaction) ----
    int s = bx - 198;
    int tid = threadIdx.x;
    __shared__ int s_base;
    __shared__ int s_wsum[4];
    if (tid == 0) s_base = 0;
    __syncthreads();
    float* P = params + s * G_N * PSTR;
    float H = (float)(100 << s);
    float sh = (float)(1 << s);
    for (int it = 0; it < G_N / 256; ++it) {
        int g = it * 256 + tid;
        float mx = means[g * 3 + 0], my = means[g * 3 + 1], mz = means[g * 3 + 2];
        float op = opac[g * 2 + s];
        bool mask = (mx >= -50.f && mx <= 50.f && my >= -50.f && my <= 50.f &&
                     mz >= -4.f && mz <= 4.f && op > 0.05f);
        unsigned long long bal = __ballot(mask);
        int lane = tid & 63, wid = tid >> 6;
        int prefix = __popcll(bal & ((1ull << lane) - 1ull));
        if (lane == 0) s_wsum[wid] = __popcll(bal);
        __syncthreads();
        int woff = 0;
        for (int w = 0; w < 4; ++w) if (w < wid) woff += s_wsum[w];
        int pos = s_base + woff + prefix;
        if (mask) {
            float u = -sh * my + 0.5f * H;
            float v = -sh * mx + 0.5f * H;
            float a = sh * sh * cov6[g * 6 + 3] + 0.3f;
            float c = sh * sh * cov6[g * 6 + 0] + 0.3f;
            float bb = sh * sh * cov6[g * 6 + 1];
            float det = fmaxf(a * c - bb * bb, 1e-8f);
            float t = logf(255.f * op);
            float* Q = P + pos * PSTR;
            Q[0] = u; Q[1] = v;
            Q[2] = c / det; Q[3] = -bb / det; Q[4] = a / det;
            Q[5] = op; Q[6] = -t;
            Q[7] = __int_as_float(g);
            Q[8] = sqrtf(2.f * t * a);
            Q[9] = sqrtf(2.f * t * c);
            Q[10] = 0.f; Q[11] = 0.f;
        }
        __syncthreads();
        if (tid == 0) s_base += s_wsum[0] + s_wsum[1] + s_wsum[2] + s_wsum[3];
        __syncthreads();
    }
    if (tid == 0) counts[s] = s_base;
}

// ---------------------------------------------------------------------------
// Render both stages: per-tile bbox cull + front-to-back composite.
// ---------------------------------------------------------------------------
__global__ __launch_bounds__(256) void gls_render(
    const float* __restrict__ params, const int* __restrict__ counts,
    const float* __restrict__ feats, float* __restrict__ out0,
    float* __restrict__ out1)
{
    int s = blockIdx.z;
    int H = 100 << s;
    if ((int)blockIdx.x * 16 >= H || (int)blockIdx.y * 16 >= H) return;
    const float* P = params + s * G_N * PSTR;
    float* out = s ? out1 : out0;
    int cnt = counts[s];

    __shared__ float raw[CCH * PSTR];
    __shared__ float cmp[CCH * PSTR];
    __shared__ int s_wsum[4];
    int tid = threadIdx.x;
    int px = blockIdx.x * 16 + (tid & 15);
    int py = blockIdx.y * 16 + (tid >> 4);
    bool active = (px < H) && (py < H);
    float fx = (float)px, fy = (float)py;
    float tx0 = (float)(blockIdx.x * 16);
    float tx1 = (float)min(H - 1, (int)blockIdx.x * 16 + 15);
    float ty0 = (float)(blockIdx.y * 16);
    float ty1 = (float)min(H - 1, (int)blockIdx.y * 16 + 15);

    float acc[64];
#pragma unroll
    for (int d = 0; d < 64; ++d) acc[d] = 0.f;
    float T = 1.f;

    for (int base = 0; base < cnt; base += CCH) {
        int anyalive = __syncthreads_or((int)(active && T > 1e-6f));
        if (!anyalive) break;
        int n = min(CCH, cnt - base);
        for (int i = tid; i < n * 3; i += 256)
            ((float4*)raw)[i] = ((const float4*)(P + base * PSTR))[i];
        __syncthreads();
        bool pass = false;
        if (tid < n) {
            float u = raw[tid * PSTR + 0], v = raw[tid * PSTR + 1];
            float rx = raw[tid * PSTR + 8], ry = raw[tid * PSTR + 9];
            pass = (u + rx >= tx0) && (u - rx <= tx1) &&
                   (v + ry >= ty0) && (v - ry <= ty1);
        }
        unsigned long long bal = __ballot(pass);
        int lane = tid & 63, wid = tid >> 6;
        int prefix = __popcll(bal & ((1ull << lane) - 1ull));
        if (lane == 0) s_wsum[wid] = __popcll(bal);
        __syncthreads();
        int woff = 0;
        for (int w = 0; w < 4; ++w) if (w < wid) woff += s_wsum[w];
        if (pass) {
            float4* dst = (float4*)(cmp + (woff + prefix) * PSTR);
            const float4* src = (const float4*)(raw + tid * PSTR);
            dst[0] = src[0]; dst[1] = src[1]; dst[2] = src[2];
        }
        __syncthreads();
        int nc = s_wsum[0] + s_wsum[1] + s_wsum[2] + s_wsum[3];
        if (active && T > 1e-6f) {
            for (int j = 0; j < nc; ++j) {
                float4 q0 = *(const float4*)(cmp + j * PSTR);
                float4 q1 = *(const float4*)(cmp + j * PSTR + 4);
                float dx = q0.x - fx, dy = q0.y - fy;
                float power = -0.5f * (q0.z * dx * dx + q1.x * dy * dy) - q0.w * dx * dy;
                if (power <= 0.f && power >= q1.z) {
                    float alpha = fminf(q1.y * __expf(power), 0.99f);
                    float wgt = alpha * T;
                    const float* f = feats + __float_as_int(q1.w) * 64;
#pragma unroll
                    for (int d = 0; d < 64; ++d) acc[d] = fmaf(wgt, f[d], acc[d]);
                    T *= (1.f - alpha);
                }
            }
        }
    }
    if (active) {
#pragma unroll
        for (int d = 0; d < 64; ++d) out[(d * H + py) * H + px] = acc[d];
    }
}

// ---------------------------------------------------------------------------
// MFMA conv3x3 64->64 v2: no split-K. Block = 4 waves, 8x8 spatial x 64 oc;
// wave w owns n-tile w (16 px) x 64 oc over the FULL K=576 -> 72 MFMA/wave,
// direct register epilogue (no cross-wave reduction).
// Two-job flattened grid (jobs run concurrently in one launch).
// mode: 0 none, 1 relu, 2 relu(conv+add), 4 conv + bev_emb[(y*W+x)*64+c]
// ups: input is H/2 NCHW f32; bilinear 2x upsample fused into LDS staging.
// ---------------------------------------------------------------------------
__global__ __launch_bounds__(256) void gls_conv2(
    const float* __restrict__ inA, const unsigned short* __restrict__ wA,
    const float* __restrict__ addA, float* __restrict__ outA,
    int HA, int modeA, int upsA, int nA,
    const float* __restrict__ inB, const unsigned short* __restrict__ wB,
    const float* __restrict__ addB, float* __restrict__ outB,
    int HB, int modeB, int upsB)
{
    __shared__ unsigned short xlds[100 * 72];   // [pos(10x10)][ci], ci-stride 72

    int bx = blockIdx.x;
    const float* in; const unsigned short* wp; const float* add; float* out;
    int H, mode, ups;
    if (bx < nA) {
        in = inA; wp = wA; add = addA; out = outA; H = HA; mode = modeA; ups = upsA;
    } else {
        bx -= nA;
        in = inB; wp = wB; add = addB; out = outB; H = HB; mode = modeB; ups = upsB;
    }
    int gw = (H + 7) >> 3;
    int by = bx / gw, bxx = bx - by * gw;
    int y0 = by * 8, x0 = bxx * 8;

    int tid = threadIdx.x;
    int w = tid >> 6, lane = tid & 63;
    int n = lane & 15, q = lane >> 4;

    // ---- stage input tile (64ci x 10x10 halo) as bf16 HWC ----
    for (int idx = tid; idx < 1600; idx += 256) {
        int ci4 = idx / 100;
        int pos = idx - ci4 * 100;
        int yy = pos / 10, xx = pos - yy * 10;
        int gy = y0 - 1 + yy, gx = x0 - 1 + xx;
        ushort4 v4 = {0, 0, 0, 0};
        if (gy >= 0 && gy < H && gx >= 0 && gx < H) {
            int ci = ci4 * 4;
            if (!ups) {
                const float* p = in + ((size_t)ci * H + gy) * H + gx;
                size_t st = (size_t)H * H;
                v4.x = f2bf(p[0]);
                v4.y = f2bf(p[st]);
                v4.z = f2bf(p[2 * st]);
                v4.w = f2bf(p[3 * st]);
            } else {
                int Hh = H >> 1;
                int yi = gy >> 1, xi = gx >> 1;
                int yb = (gy & 1) ? min(yi + 1, Hh - 1) : max(yi - 1, 0);
                int xb = (gx & 1) ? min(xi + 1, Hh - 1) : max(xi - 1, 0);
                int i00 = yi * Hh + xi, i01 = yi * Hh + xb;
                int i10 = yb * Hh + xi, i11 = yb * Hh + xb;
                unsigned short r[4];
#pragma unroll
                for (int k = 0; k < 4; ++k) {
                    const float* p = in + (size_t)(ci + k) * Hh * Hh;
                    r[k] = f2bf(0.5625f * p[i00] + 0.1875f * p[i01]
                              + 0.1875f * p[i10] + 0.0625f * p[i11]);
                }
                v4.x = r[0]; v4.y = r[1]; v4.z = r[2]; v4.w = r[3];
            }
        }
        *(ushort4*)&xlds[pos * 72 + ci4 * 4] = v4;
    }
    __syncthreads();

    // ---- full-K loop, software-pipelined: 18 (tap,chunk) pairs x 4 MFMA ----
    f32x4 acc[4];
#pragma unroll
    for (int m = 0; m < 4; ++m) acc[m] = (f32x4){0.f, 0.f, 0.f, 0.f};

    const bhalf8* wp8 = (const bhalf8*)wp;
    int sy = 2 * w + (n >> 3), sx = n & 7;

    bhalf8 a0 = wp8[(0 * 4 + 0) * 64 + lane];
    bhalf8 a1 = wp8[(0 * 4 + 1) * 64 + lane];
    bhalf8 a2 = wp8[(0 * 4 + 2) * 64 + lane];
    bhalf8 a3 = wp8[(0 * 4 + 3) * 64 + lane];
    bhalf8 bb = *(const bhalf8*)&xlds[(sy * 10 + sx) * 72 + q * 8];  // tap0 ch0: dy=dx=0

#pragma unroll 1
    for (int p = 0; p < 18; ++p) {
        bhalf8 na0, na1, na2, na3, nbb;
        if (p < 17) {
            int pn = p + 1;
            na0 = wp8[(pn * 4 + 0) * 64 + lane];
            na1 = wp8[(pn * 4 + 1) * 64 + lane];
            na2 = wp8[(pn * 4 + 2) * 64 + lane];
            na3 = wp8[(pn * 4 + 3) * 64 + lane];
            int tap = pn >> 1, ch = pn & 1;
            int dy = tap / 3, dx = tap - dy * 3;
            nbb = *(const bhalf8*)&xlds[((sy + dy) * 10 + sx + dx) * 72 + ch * 32 + q * 8];
        }
        acc[0] = __builtin_amdgcn_mfma_f32_16x16x32_bf16(a0, bb, acc[0], 0, 0, 0);
        acc[1] = __builtin_amdgcn_mfma_f32_16x16x32_bf16(a1, bb, acc[1], 0, 0, 0);
        acc[2] = __builtin_amdgcn_mfma_f32_16x16x32_bf16(a2, bb, acc[2], 0, 0, 0);
        acc[3] = __builtin_amdgcn_mfma_f32_16x16x32_bf16(a3, bb, acc[3], 0, 0, 0);
        a0 = na0; a1 = na1; a2 = na2; a3 = na3; bb = nbb;
    }

    // ---- direct epilogue: lane covers px (y0+sy, x0+sx), oc = m*16+q*4+r ----
    int gy = y0 + sy, gx = x0 + sx;
    if (gy < H && gx < H) {
#pragma unroll
        for (int m = 0; m < 4; ++m) {
#pragma unroll
            for (int r = 0; r < 4; ++r) {
                int oc = m * 16 + q * 4 + r;
                float v = acc[m][r];
                int idxo = (oc * H + gy) * H + gx;
                if (mode == 1) v = fmaxf(v, 0.f);
                else if (mode == 2) v = fmaxf(v + add[idxo], 0.f);
                else if (mode == 4) v = v + add[(gy * H + gx) * 64 + oc];
                out[idxo] = v;
            }
        }
    }
}

// ---------------------------------------------------------------------------
// Instance norm reduce: per-channel mean / inv-std over 200x200 (float4).
// ---------------------------------------------------------------------------
__global__ __launch_bounds__(256) void gls_in_reduce(const float* __restrict__ y,
                                                     float* __restrict__ stats)
{
    int c = blockIdx.x;
    const float4* p = (const float4*)(y + (size_t)c * 40000);
    float s = 0.f, s2 = 0.f;
    for (int i = threadIdx.x; i < 10000; i += 256) {
        float4 v = p[i];
        s += v.x + v.y + v.z + v.w;
        s2 = fmaf(v.x, v.x, s2); s2 = fmaf(v.y, v.y, s2);
        s2 = fmaf(v.z, v.z, s2); s2 = fmaf(v.w, v.w, s2);
    }
    __shared__ float ls[256], ls2[256];
    ls[threadIdx.x] = s; ls2[threadIdx.x] = s2;
    __syncthreads();
    for (int off = 128; off > 0; off >>= 1) {
        if (threadIdx.x < off) {
            ls[threadIdx.x] += ls[threadIdx.x + off];
            ls2[threadIdx.x] += ls2[threadIdx.x + off];
        }
        __syncthreads();
    }
    if (threadIdx.x == 0) {
        float mean = ls[0] / 40000.f;
        float var = ls2[0] / 40000.f - mean * mean;
        stats[c] = mean;
        stats[64 + c] = rsqrtf(var + 1e-5f);
    }
}

// normadd (float4) + num_g write fused.
__global__ void gls_normadd(const float* __restrict__ y, const float* __restrict__ stats,
                            const float* __restrict__ c1, float* __restrict__ out,
                            const int* __restrict__ counts, float* __restrict__ numg)
{
    int i4 = blockIdx.x * 256 + threadIdx.x;
    if (i4 == 0) numg[0] = (float)(counts[0] + counts[1]);
    if (i4 >= 640000) return;
    int c = i4 / 10000;
    float mean = stats[c], rstd = stats[64 + c];
    float4 v = ((const float4*)y)[i4];
    float4 a = ((const float4*)c1)[i4];
    float4 o;
    o.x = (v.x - mean) * rstd + a.x;
    o.y = (v.y - mean) * rstd + a.y;
    o.z = (v.z - mean) * rstd + a.z;
    o.w = (v.w - mean) * rstd + a.w;
    ((float4*)out)[i4] = o;
}

// ---------------------------------------------------------------------------
extern "C" void kernel_launch(void* const* d_in, const int* in_sizes, int n_in,
                              void* d_out, int out_size, void* d_ws, size_t ws_size,
                              hipStream_t stream)
{
    const float* feats   = (const float*)d_in[0];
    const float* means   = (const float*)d_in[1];
    const float* cov6    = (const float*)d_in[2];
    const float* opac    = (const float*)d_in[3];
    const float* bev_emb = (const float*)d_in[4];
    const float* conv1_w = (const float*)d_in[5];
    const float* blk_w   = (const float*)d_in[6];
    const float* up_w    = (const float*)d_in[7];
    float* out = (float*)d_out;
    float* ws = (float*)d_ws;

    const int WC = 64 * 64 * 9;  // wprep elems per conv

    float* P     = ws;                         // 49152 floats
    int*   cnts  = (int*)(ws + 49152);
    float* stats = ws + 49408;
    unsigned short* wprep = (unsigned short*)(ws + 49664);  // 11*36864 u16
    float* R0 = ws + 262144;                   // 640000 (H=100 buffers)
    float* A0 = ws + 917504;
    float* T0 = ws + 1572864;
    float* B0 = ws + 2228224;
    float* Q0 = ws + 2883584;                  // 2560000 (H=200 buffers)
    float* Q1 = ws + 5505024;
    float* Q2 = ws + 8126464;
    float* Q3 = ws + 10747904;

    gls_prep<<<200, 256, 0, stream>>>(conv1_w, blk_w, up_w, wprep,
                                      means, cov6, opac, P, cnts);
    gls_render<<<dim3(13, 13, 2), 256, 0, stream>>>(P, cnts, feats, R0, Q0);

    // L1: c0 (H100, +bev_emb) CONCURRENT WITH c5 (H200 skip conv) — both only need render.
    gls_conv2<<<169 + 625, 256, 0, stream>>>(
        R0, wprep + 0 * WC, bev_emb, A0, 100, 4, 0, 169,
        Q0, wprep + 5 * WC, nullptr, Q1, 200, 0, 0);
    // H100 basic blocks
    gls_conv2<<<169, 256, 0, stream>>>(A0, wprep + 1 * WC, nullptr, T0, 100, 1, 0, 169,
                                       nullptr, nullptr, nullptr, nullptr, 0, 0, 0);
    gls_conv2<<<169, 256, 0, stream>>>(T0, wprep + 2 * WC, A0, B0, 100, 2, 0, 169,
                                       nullptr, nullptr, nullptr, nullptr, 0, 0, 0);
    gls_conv2<<<169, 256, 0, stream>>>(B0, wprep + 3 * WC, nullptr, T0, 100, 1, 0, 169,
                                       nullptr, nullptr, nullptr, nullptr, 0, 0, 0);
    gls_conv2<<<169, 256, 0, stream>>>(T0, wprep + 4 * WC, B0, A0, 100, 2, 0, 169,
                                       nullptr, nullptr, nullptr, nullptr, 0, 0, 0);
    // up-conv with fused bilinear upsample: A0 (H100) -> Q3 (H200)
    gls_conv2<<<625, 256, 0, stream>>>(A0, wprep + 6 * WC, nullptr, Q3, 200, 0, 1, 625,
                                       nullptr, nullptr, nullptr, nullptr, 0, 0, 0);
    gls_in_reduce<<<64, 256, 0, stream>>>(Q3, stats);
    gls_normadd<<<2500, 256, 0, stream>>>(Q3, stats, Q1, Q0, cnts, out + 2560000);
    // H200 basic blocks, final conv writes d_out
    gls_conv2<<<625, 256, 0, stream>>>(Q0, wprep + 7 * WC, nullptr, Q2, 200, 1, 0, 625,
                                       nullptr, nullptr, nullptr, nullptr, 0, 0, 0);
    gls_conv2<<<625, 256, 0, stream>>>(Q2, wprep + 8 * WC, Q0, Q1, 200, 2, 0, 625,
                                       nullptr, nullptr, nullptr, nullptr, 0, 0, 0);
    gls_conv2<<<625, 256, 0, stream>>>(Q1, wprep + 9 * WC, nullptr, Q2, 200, 1, 0, 625,
                                       nullptr, nullptr, nullptr, nullptr, 0, 0, 0);
    gls_conv2<<<625, 256, 0, stream>>>(Q2, wprep + 10 * WC, Q1, out, 200, 2, 0, 625,
                                       nullptr, nullptr, nullptr, nullptr, 0, 0, 0);

    (void)in_sizes; (void)n_in; (void)out_size; (void)ws_size;
}